// Round 4
// baseline (369.745 us; speedup 1.0000x reference)
//
#include <hip/hip_runtime.h>

typedef __attribute__((ext_vector_type(8))) short s16x8;
typedef __attribute__((ext_vector_type(4))) short s16x4;
typedef __attribute__((ext_vector_type(4))) float f32x4;
typedef unsigned short u16;
typedef unsigned int u32;
typedef unsigned long long u64;

__device__ __forceinline__ u16 f2bf(float f) {
  unsigned u = __builtin_bit_cast(unsigned, f);
  return (u16)((u + 0x7fffu + ((u >> 16) & 1u)) >> 16);  // RNE fp32->bf16
}

// 0.125 (1/sqrt(dh)) * log2(e): scores in log2 domain for v_exp_f32
#define QSCALE 0.18033688011112042f

// async global->LDS, 16B per lane; LDS dst is wave-uniform base + lane*16
__device__ __forceinline__ void gld16(const u16* g, u16* l) {
  __builtin_amdgcn_global_load_lds(
      (const __attribute__((address_space(1))) void*)g,
      (__attribute__((address_space(3))) void*)l, 16, 0, 0);
}

// pack hi16(a),hi16(b) -> [bf16(a) | bf16(b)<<16]  (truncation, 1 op)
__device__ __forceinline__ u32 pack_trunc(float a, float b) {
  return __builtin_amdgcn_perm(__builtin_bit_cast(u32, b),
                               __builtin_bit_cast(u32, a), 0x07060302u);
}

// ---------------------------------------------------------------------------
// fp32 -> bf16 convert, 8 elems/thread
// ---------------------------------------------------------------------------
__global__ __launch_bounds__(256)
void cvt_bf16(const float* __restrict__ src, u16* __restrict__ dst, int n8)
{
  const int i = blockIdx.x * 256 + threadIdx.x;
  if (i < n8) {
    f32x4 a = ((const f32x4*)src)[2 * i];
    f32x4 b = ((const f32x4*)src)[2 * i + 1];
    s16x8 pk;
    pk[0] = (short)f2bf(a[0]); pk[1] = (short)f2bf(a[1]);
    pk[2] = (short)f2bf(a[2]); pk[3] = (short)f2bf(a[3]);
    pk[4] = (short)f2bf(b[0]); pk[5] = (short)f2bf(b[1]);
    pk[6] = (short)f2bf(b[2]); pk[7] = (short)f2bf(b[3]);
    ((s16x8*)dst)[i] = pk;
  }
}

// ---------------------------------------------------------------------------
// m97-structure GEMM. Grid: (m-tiles, n-tiles, z). m-tile on blockIdx.x so
// round-robin XCD dispatch pins m-tiles to XCDs: XCD k re-reads only its
// own 2MB slice of A across all (n,z) -> A stays L2-resident.
// ---------------------------------------------------------------------------
template<bool OUT_QKV>
__global__ __launch_bounds__(256)
void gemm97(const u16* __restrict__ A,
            const u16* __restrict__ B0, const u16* __restrict__ B1,
            const u16* __restrict__ B2,
            u16* __restrict__ o0, u16* __restrict__ o1, u16* __restrict__ o2,
            float* __restrict__ oF)
{
  const int by = blockIdx.x;   // m-tile (XCD-pinned)
  const int bx = blockIdx.y;   // n-tile
  const int bz = blockIdx.z;
  const u16* B = (bz == 0) ? B0 : ((bz == 1) ? B1 : B2);
  u16* oQ = (bz == 0) ? o0 : ((bz == 1) ? o1 : o2);

  __shared__ u16 As[128 * 32];
  __shared__ u16 Bs[128 * 32];

  const int tid  = threadIdx.x;
  const int w    = tid >> 6;
  const int lane = tid & 63;
  const int quad = lane >> 4;
  const int l15  = lane & 15;
  const int wm   = (w >> 1) * 64;
  const int wn   = (w & 1) * 64;

  const int arb  = w * 32;
  const int srow = lane >> 2;
  const int scol = (lane & 3) * 8;
  const u16* ga = A + (size_t)(by * 128 + arb + srow) * 1024 + scol;
  const u16* gb = B + (size_t)(bx * 128 + arb + srow) * 1024 + scol;
  u16* la0 = &As[arb * 32];
  u16* la1 = &As[(arb + 16) * 32];
  u16* lb0 = &Bs[arb * 32];
  u16* lb1 = &Bs[(arb + 16) * 32];

  f32x4 acc[4][4];
  #pragma unroll
  for (int i = 0; i < 4; ++i)
    #pragma unroll
    for (int j = 0; j < 4; ++j)
      acc[i][j] = (f32x4){0.f, 0.f, 0.f, 0.f};

  for (int k0 = 0; k0 < 1024; k0 += 32) {
    gld16(ga + k0,               la0);
    gld16(ga + k0 + 16 * 1024,   la1);
    gld16(gb + k0,               lb0);
    gld16(gb + k0 + 16 * 1024,   lb1);
    __syncthreads();

    s16x8 af[4], bf[4];
    #pragma unroll
    for (int i = 0; i < 4; ++i)
      af[i] = *(const s16x8*)&As[(wm + i * 16 + l15) * 32 + quad * 8];
    #pragma unroll
    for (int i = 0; i < 4; ++i)
      bf[i] = *(const s16x8*)&Bs[(wn + i * 16 + l15) * 32 + quad * 8];
    #pragma unroll
    for (int mt = 0; mt < 4; ++mt)
      #pragma unroll
      for (int nt = 0; nt < 4; ++nt)
        acc[mt][nt] = __builtin_amdgcn_mfma_f32_16x16x32_bf16(
            af[mt], bf[nt], acc[mt][nt], 0, 0, 0);
    __syncthreads();
  }

  #pragma unroll
  for (int mt = 0; mt < 4; ++mt)
    #pragma unroll
    for (int nt = 0; nt < 4; ++nt)
      #pragma unroll
      for (int r = 0; r < 4; ++r) {
        const int row = by * 128 + wm + mt * 16 + quad * 4 + r;
        const int col = bx * 128 + wn + nt * 16 + l15;
        float v = acc[mt][nt][r];
        if (OUT_QKV) {
          if (bz == 0) v *= QSCALE;
          const int b = row >> 11, s = row & 2047, hh = col >> 6, d = col & 63;
          oQ[(size_t)(b * 16 + hh) * 131072 + s * 64 + d] = f2bf(v);
        } else {
          oF[(size_t)row * 1024 + col] = v;
        }
      }
}

// ---------------------------------------------------------------------------
// V transpose: [bh][2048][64] -> [bh][64][2048] (bf16)
// ---------------------------------------------------------------------------
__global__ __launch_bounds__(256)
void vtrans(const u16* __restrict__ Vb, u16* __restrict__ VT)
{
  const int st = blockIdx.x;
  const int bh = blockIdx.y;
  __shared__ u16 T[64 * 72];
  const int tid = threadIdx.x;
  const size_t base = (size_t)bh * 131072;
  #pragma unroll
  for (int p = 0; p < 2; ++p) {
    const int idx = tid + p * 256;
    const int row = idx >> 3;
    const int col = (idx & 7) * 8;
    s16x8 v = *(const s16x8*)(Vb + base + (size_t)(st * 64 + row) * 64 + col);
    #pragma unroll
    for (int e = 0; e < 8; ++e) T[(col + e) * 72 + row] = v[e];
  }
  __syncthreads();
  #pragma unroll
  for (int p = 0; p < 2; ++p) {
    const int idx = tid + p * 256;
    const int drow = idx >> 3;
    const int scol = (idx & 7) * 8;
    *(s16x8*)(VT + base + (size_t)drow * 2048 + st * 64 + scol) =
        *(const s16x8*)&T[drow * 72 + scol];
  }
}

// ---------------------------------------------------------------------------
// Causal flash attention, all-waves-both-tiles: block pi owns q-tiles
// {31-pi, pi} (64 rows each); EVERY wave processes 16 rows of EACH tile.
// Light-tile compute gated by j<=qt[1] (block-uniform) -> no idle barriers.
// K staged permuted (slot=(key&3)*16+key>>2) so lane's 4 S cols are keys
// 4*l15..+3; P packed by byte-perm truncation (1 op / 2 values).
// ---------------------------------------------------------------------------
__global__ __launch_bounds__(256, 4)
void attn_kernel(const u16* __restrict__ Qg, const u16* __restrict__ Kg,
                 const u16* __restrict__ VTg, u16* __restrict__ out)
{
  const int pi = blockIdx.x;
  const int bh = blockIdx.y;
  const int b = bh >> 4, h = bh & 15;
  const int qt0 = 31 - pi;            // heavy tile
  const int qt1 = pi;                 // light tile

  __shared__ u16 Qs[128 * 72];        // rows 0-63: qt0, 64-127: qt1; P scratch
  __shared__ u16 Ks[64 * 72];
  __shared__ u16 Vt[64 * 72];

  const int tid = threadIdx.x;
  const int w = tid >> 6, lane = tid & 63, quad = lane >> 4, l15 = lane & 15;
  const size_t base = (size_t)bh * 131072;

  {
    const int col = (tid & 7) * 8;
    #pragma unroll
    for (int p = 0; p < 4; ++p) {
      const int row = (tid >> 3) + p * 32;
      const int gq = (row < 64) ? (qt0 * 64 + row) : (qt1 * 64 + (row - 64));
      *(s16x8*)&Qs[row * 72 + col] =
          *(const s16x8*)(Qg + base + (size_t)gq * 64 + col);
    }
  }
  __syncthreads();

  // per-wave 16-row slices: tile t rows [t*64 + w*16, +16)
  s16x8 aq[2][2];
  #pragma unroll
  for (int t = 0; t < 2; ++t)
    #pragma unroll
    for (int ks = 0; ks < 2; ++ks)
      aq[t][ks] = *(const s16x8*)&Qs[(t * 64 + w * 16 + l15) * 72 + ks * 32 + quad * 8];

  u16* Pw0 = &Qs[(w * 16) * 72];
  u16* Pw1 = &Qs[(64 + w * 16) * 72];

  s16x8 ones;
  #pragma unroll
  for (int e = 0; e < 8; ++e) ones[e] = (short)0x3F80;

  f32x4 O[2][4], liacc[2];
  float mi[2][4];
  #pragma unroll
  for (int t = 0; t < 2; ++t) {
    #pragma unroll
    for (int dt = 0; dt < 4; ++dt) O[t][dt] = (f32x4){0.f, 0.f, 0.f, 0.f};
    liacc[t] = (f32x4){0.f, 0.f, 0.f, 0.f};
    #pragma unroll
    for (int r = 0; r < 4; ++r) mi[t][r] = -1e30f;
  }

  for (int j = 0; j <= qt0; ++j) {
    #pragma unroll
    for (int p = 0; p < 2; ++p) {
      const int idx = tid + p * 256;
      const int key = idx >> 3, col = (idx & 7) * 8;
      const int slot = (key & 3) * 16 + (key >> 2);
      *(s16x8*)&Ks[slot * 72 + col] =
          *(const s16x8*)(Kg + base + (size_t)(j * 64 + key) * 64 + col);
    }
    #pragma unroll
    for (int p = 0; p < 2; ++p) {
      const int idx = tid + p * 256;
      const int d = idx >> 3, col = (idx & 7) * 8;
      *(s16x8*)&Vt[d * 72 + col] =
          *(const s16x8*)(VTg + base + (size_t)d * 2048 + j * 64 + col);
    }
    __syncthreads();

    const int nact = (j <= qt1) ? 2 : 1;
    for (int t = 0; t < nact; ++t) {
      u16* Pw = t ? Pw1 : Pw0;
      const int qtt = t ? qt1 : qt0;
      // S = Q K^T (log2 domain; col of tile nt = key 4*l15+nt)
      f32x4 S[4];
      #pragma unroll
      for (int nt = 0; nt < 4; ++nt) {
        s16x8 b0 = *(const s16x8*)&Ks[(nt * 16 + l15) * 72 + quad * 8];
        s16x8 b1 = *(const s16x8*)&Ks[(nt * 16 + l15) * 72 + 32 + quad * 8];
        f32x4 z = (f32x4){0.f, 0.f, 0.f, 0.f};
        z = __builtin_amdgcn_mfma_f32_16x16x32_bf16(aq[t][0], b0, z, 0, 0, 0);
        z = __builtin_amdgcn_mfma_f32_16x16x32_bf16(aq[t][1], b1, z, 0, 0, 0);
        S[nt] = z;
      }
      if (j == qtt) {  // diagonal tile
        #pragma unroll
        for (int nt = 0; nt < 4; ++nt)
          #pragma unroll
          for (int r = 0; r < 4; ++r) {
            const int kg = 4 * l15 + nt;
            const int qg = w * 16 + quad * 4 + r;
            if (kg > qg) S[nt][r] = -1e30f;
          }
      }
      // online softmax (rows live across the 16 l15-lanes of each quad)
      #pragma unroll
      for (int r = 0; r < 4; ++r) {
        float rm = fmaxf(fmaxf(S[0][r], S[1][r]), fmaxf(S[2][r], S[3][r]));
        #pragma unroll
        for (int off = 1; off < 16; off <<= 1)
          rm = fmaxf(rm, __shfl_xor(rm, off, 64));
        const float mold = mi[t][r];
        const float mnew = fmaxf(mold, rm);
        const float alpha = __builtin_amdgcn_exp2f(mold - mnew);
        mi[t][r] = mnew;
        const float p0 = __builtin_amdgcn_exp2f(S[0][r] - mnew);
        const float p1 = __builtin_amdgcn_exp2f(S[1][r] - mnew);
        const float p2 = __builtin_amdgcn_exp2f(S[2][r] - mnew);
        const float p3 = __builtin_amdgcn_exp2f(S[3][r] - mnew);
        liacc[t][r] *= alpha;
        #pragma unroll
        for (int dt = 0; dt < 4; ++dt) O[t][dt][r] *= alpha;
        const u64 pk = (u64)pack_trunc(p0, p1) |
                       ((u64)pack_trunc(p2, p3) << 32);
        *(u64*)&Pw[(quad * 4 + r) * 72 + 4 * l15] = pk;
      }
      // PV + row-sum MFMA
      s16x8 a0 = *(const s16x8*)&Pw[l15 * 72 + quad * 8];
      s16x8 a1 = *(const s16x8*)&Pw[l15 * 72 + 32 + quad * 8];
      liacc[t] = __builtin_amdgcn_mfma_f32_16x16x32_bf16(a0, ones, liacc[t], 0, 0, 0);
      liacc[t] = __builtin_amdgcn_mfma_f32_16x16x32_bf16(a1, ones, liacc[t], 0, 0, 0);
      #pragma unroll
      for (int dt = 0; dt < 4; ++dt) {
        s16x8 b0 = *(const s16x8*)&Vt[(dt * 16 + l15) * 72 + quad * 8];
        s16x8 b1 = *(const s16x8*)&Vt[(dt * 16 + l15) * 72 + 32 + quad * 8];
        O[t][dt] = __builtin_amdgcn_mfma_f32_16x16x32_bf16(a0, b0, O[t][dt], 0, 0, 0);
        O[t][dt] = __builtin_amdgcn_mfma_f32_16x16x32_bf16(a1, b1, O[t][dt], 0, 0, 0);
      }
    }
    __syncthreads();
  }

  #pragma unroll
  for (int t = 0; t < 2; ++t) {
    const int qtt = t ? qt1 : qt0;
    #pragma unroll
    for (int r = 0; r < 4; ++r) {
      const float inv = __builtin_amdgcn_rcpf(liacc[t][r]);
      const int sq = qtt * 64 + w * 16 + quad * 4 + r;
      #pragma unroll
      for (int dt = 0; dt < 4; ++dt)
        out[(size_t)(b * 2048 + sq) * 1024 + h * 64 + dt * 16 + l15] =
            f2bf(O[t][dt][r] * inv);
    }
  }
}

extern "C" void kernel_launch(void* const* d_in, const int* in_sizes, int n_in,
                              void* d_out, int out_size, void* d_ws, size_t ws_size,
                              hipStream_t stream) {
  (void)in_sizes; (void)n_in; (void)out_size; (void)ws_size;
  const float* x  = (const float*)d_in[0];
  const float* Wq = (const float*)d_in[1];
  const float* Wk = (const float*)d_in[2];
  const float* Wv = (const float*)d_in[3];
  const float* Wo = (const float*)d_in[4];
  float* out = (float*)d_out;

  u16* W16 = (u16*)d_ws;
  u16* xb  = W16;
  u16* VT  = W16;                 // alias: x dead after QKV gemm
  u16* Qb  = W16 + 8388608;
  u16* Kb  = W16 + 16777216;
  u16* Vb  = W16 + 25165824;
  u16* AO  = Vb;                  // alias: V natural layout dead after vtrans
  u16* Wqb = W16 + 33554432;
  u16* Wkb = Wqb + 1048576;
  u16* Wvb = Wkb + 1048576;
  u16* Wob = Wvb + 1048576;

  dim3 blk(256);
  cvt_bf16<<<dim3(4096), blk, 0, stream>>>(x,  xb,  1048576);
  cvt_bf16<<<dim3(512),  blk, 0, stream>>>(Wq, Wqb, 131072);
  cvt_bf16<<<dim3(512),  blk, 0, stream>>>(Wk, Wkb, 131072);
  cvt_bf16<<<dim3(512),  blk, 0, stream>>>(Wv, Wvb, 131072);
  cvt_bf16<<<dim3(512),  blk, 0, stream>>>(Wo, Wob, 131072);

  gemm97<true ><<<dim3(64, 8, 3), blk, 0, stream>>>(
      xb, Wqb, Wkb, Wvb, Qb, Kb, Vb, nullptr);
  vtrans<<<dim3(32, 64), blk, 0, stream>>>(Vb, VT);
  attn_kernel<<<dim3(16, 64), blk, 0, stream>>>(Qb, Kb, VT, AO);
  gemm97<false><<<dim3(64, 8, 1), blk, 0, stream>>>(
      AO, Wob, Wob, Wob, nullptr, nullptr, nullptr, out);
}

// Round 5
// 284.179 us; speedup vs baseline: 1.3011x; 1.3011x over previous
//
#include <hip/hip_runtime.h>

typedef __attribute__((ext_vector_type(8))) short s16x8;
typedef __attribute__((ext_vector_type(4))) short s16x4;
typedef __attribute__((ext_vector_type(4))) float f32x4;
typedef unsigned short u16;
typedef unsigned int u32;
typedef unsigned long long u64;

__device__ __forceinline__ u16 f2bf(float f) {
  unsigned u = __builtin_bit_cast(unsigned, f);
  return (u16)((u + 0x7fffu + ((u >> 16) & 1u)) >> 16);  // RNE fp32->bf16
}

// 0.125 (1/sqrt(dh)) * log2(e): scores in log2 domain for v_exp_f32
#define QSCALE 0.18033688011112042f

// async global->LDS, 16B per lane; LDS dst is wave-uniform base + lane*16
__device__ __forceinline__ void gld16(const u16* g, u16* l) {
  __builtin_amdgcn_global_load_lds(
      (const __attribute__((address_space(1))) void*)g,
      (__attribute__((address_space(3))) void*)l, 16, 0, 0);
}

// v_perm: D = [bf16(a) | bf16(b)<<16] by byte-select (truncating pack, 1 op)
__device__ __forceinline__ u32 pack_trunc(float a, float b) {
  return __builtin_amdgcn_perm(__builtin_bit_cast(u32, b),
                               __builtin_bit_cast(u32, a), 0x07060302u);
}

// ---------------------------------------------------------------------------
// fp32 -> bf16 convert, 8 elems/thread
// ---------------------------------------------------------------------------
__global__ __launch_bounds__(256)
void cvt_bf16(const float* __restrict__ src, u16* __restrict__ dst, int n8)
{
  const int i = blockIdx.x * 256 + threadIdx.x;
  if (i < n8) {
    f32x4 a = ((const f32x4*)src)[2 * i];
    f32x4 b = ((const f32x4*)src)[2 * i + 1];
    s16x8 pk;
    pk[0] = (short)f2bf(a[0]); pk[1] = (short)f2bf(a[1]);
    pk[2] = (short)f2bf(a[2]); pk[3] = (short)f2bf(a[3]);
    pk[4] = (short)f2bf(b[0]); pk[5] = (short)f2bf(b[1]);
    pk[6] = (short)f2bf(b[2]); pk[7] = (short)f2bf(b[3]);
    ((s16x8*)dst)[i] = pk;
  }
}

// ---------------------------------------------------------------------------
// m97-structure GEMM. Grid: (m-tiles, n-tiles, z); m-tile on x -> XCD-pinned.
// ---------------------------------------------------------------------------
template<bool OUT_QKV>
__global__ __launch_bounds__(256)
void gemm97(const u16* __restrict__ A,
            const u16* __restrict__ B0, const u16* __restrict__ B1,
            const u16* __restrict__ B2,
            u16* __restrict__ o0, u16* __restrict__ o1, u16* __restrict__ o2,
            float* __restrict__ oF)
{
  const int by = blockIdx.x;   // m-tile (XCD-pinned)
  const int bx = blockIdx.y;   // n-tile
  const int bz = blockIdx.z;
  const u16* B = (bz == 0) ? B0 : ((bz == 1) ? B1 : B2);
  u16* oQ = (bz == 0) ? o0 : ((bz == 1) ? o1 : o2);

  __shared__ u16 As[128 * 32];
  __shared__ u16 Bs[128 * 32];

  const int tid  = threadIdx.x;
  const int w    = tid >> 6;
  const int lane = tid & 63;
  const int quad = lane >> 4;
  const int l15  = lane & 15;
  const int wm   = (w >> 1) * 64;
  const int wn   = (w & 1) * 64;

  const int arb  = w * 32;
  const int srow = lane >> 2;
  const int scol = (lane & 3) * 8;
  const u16* ga = A + (size_t)(by * 128 + arb + srow) * 1024 + scol;
  const u16* gb = B + (size_t)(bx * 128 + arb + srow) * 1024 + scol;
  u16* la0 = &As[arb * 32];
  u16* la1 = &As[(arb + 16) * 32];
  u16* lb0 = &Bs[arb * 32];
  u16* lb1 = &Bs[(arb + 16) * 32];

  f32x4 acc[4][4];
  #pragma unroll
  for (int i = 0; i < 4; ++i)
    #pragma unroll
    for (int j = 0; j < 4; ++j)
      acc[i][j] = (f32x4){0.f, 0.f, 0.f, 0.f};

  for (int k0 = 0; k0 < 1024; k0 += 32) {
    gld16(ga + k0,               la0);
    gld16(ga + k0 + 16 * 1024,   la1);
    gld16(gb + k0,               lb0);
    gld16(gb + k0 + 16 * 1024,   lb1);
    __syncthreads();

    s16x8 af[4], bf[4];
    #pragma unroll
    for (int i = 0; i < 4; ++i)
      af[i] = *(const s16x8*)&As[(wm + i * 16 + l15) * 32 + quad * 8];
    #pragma unroll
    for (int i = 0; i < 4; ++i)
      bf[i] = *(const s16x8*)&Bs[(wn + i * 16 + l15) * 32 + quad * 8];
    #pragma unroll
    for (int mt = 0; mt < 4; ++mt)
      #pragma unroll
      for (int nt = 0; nt < 4; ++nt)
        acc[mt][nt] = __builtin_amdgcn_mfma_f32_16x16x32_bf16(
            af[mt], bf[nt], acc[mt][nt], 0, 0, 0);
    __syncthreads();
  }

  #pragma unroll
  for (int mt = 0; mt < 4; ++mt)
    #pragma unroll
    for (int nt = 0; nt < 4; ++nt)
      #pragma unroll
      for (int r = 0; r < 4; ++r) {
        const int row = by * 128 + wm + mt * 16 + quad * 4 + r;
        const int col = bx * 128 + wn + nt * 16 + l15;
        float v = acc[mt][nt][r];
        if (OUT_QKV) {
          if (bz == 0) v *= QSCALE;
          const int b = row >> 11, s = row & 2047, hh = col >> 6, d = col & 63;
          oQ[(size_t)(b * 16 + hh) * 131072 + s * 64 + d] = f2bf(v);
        } else {
          oF[(size_t)row * 1024 + col] = v;
        }
      }
}

// ---------------------------------------------------------------------------
// V transpose: [bh][2048][64] -> [bh][64][2048] (bf16)
// ---------------------------------------------------------------------------
__global__ __launch_bounds__(256)
void vtrans(const u16* __restrict__ Vb, u16* __restrict__ VT)
{
  const int st = blockIdx.x;
  const int bh = blockIdx.y;
  __shared__ u16 T[64 * 72];
  const int tid = threadIdx.x;
  const size_t base = (size_t)bh * 131072;
  #pragma unroll
  for (int p = 0; p < 2; ++p) {
    const int idx = tid + p * 256;
    const int row = idx >> 3;
    const int col = (idx & 7) * 8;
    s16x8 v = *(const s16x8*)(Vb + base + (size_t)(st * 64 + row) * 64 + col);
    #pragma unroll
    for (int e = 0; e < 8; ++e) T[(col + e) * 72 + row] = v[e];
  }
  __syncthreads();
  #pragma unroll
  for (int p = 0; p < 2; ++p) {
    const int idx = tid + p * 256;
    const int drow = idx >> 3;
    const int scol = (idx & 7) * 8;
    *(s16x8*)(VT + base + (size_t)drow * 2048 + st * 64 + scol) =
        *(const s16x8*)&T[drow * 72 + scol];
  }
}

// ---------------------------------------------------------------------------
// Causal flash attention, all-waves-both-tiles, COMPILE-TIME tile index.
// Block pi owns q-tiles {31-pi, pi}; every wave processes 16 rows of each.
// The t=1 body runs under the block-uniform guard j<=qt1 (scalar branch).
// ATTN_STEP is a macro so t, and thus all aq/O/mi/liacc indices, are
// compile-time constants -> everything stays in registers (the Round-4
// runtime-t loop spilled all accumulators to scratch: WRITE_SIZE 228MB).
// ---------------------------------------------------------------------------
#define ATTN_STEP(t, Pw, qtt)                                                  \
  do {                                                                         \
    f32x4 S[4];                                                                \
    _Pragma("unroll")                                                          \
    for (int nt = 0; nt < 4; ++nt) {                                           \
      s16x8 b0 = *(const s16x8*)&Ks[(nt * 16 + l15) * 72 + quad * 8];          \
      s16x8 b1 = *(const s16x8*)&Ks[(nt * 16 + l15) * 72 + 32 + quad * 8];     \
      f32x4 z = (f32x4){0.f, 0.f, 0.f, 0.f};                                   \
      z = __builtin_amdgcn_mfma_f32_16x16x32_bf16(aq[t][0], b0, z, 0, 0, 0);   \
      z = __builtin_amdgcn_mfma_f32_16x16x32_bf16(aq[t][1], b1, z, 0, 0, 0);   \
      S[nt] = z;                                                               \
    }                                                                          \
    if (j == (qtt)) {                                                          \
      _Pragma("unroll")                                                        \
      for (int nt = 0; nt < 4; ++nt)                                           \
        _Pragma("unroll")                                                      \
        for (int r = 0; r < 4; ++r) {                                          \
          const int kg = 4 * l15 + nt;                                         \
          const int qg = w * 16 + quad * 4 + r;                                \
          if (kg > qg) S[nt][r] = -1e30f;                                      \
        }                                                                      \
    }                                                                          \
    _Pragma("unroll")                                                          \
    for (int r = 0; r < 4; ++r) {                                              \
      float rm = fmaxf(fmaxf(S[0][r], S[1][r]), fmaxf(S[2][r], S[3][r]));      \
      _Pragma("unroll")                                                        \
      for (int off = 1; off < 16; off <<= 1)                                   \
        rm = fmaxf(rm, __shfl_xor(rm, off, 64));                               \
      const float mold = mi[t][r];                                             \
      const float mnew = fmaxf(mold, rm);                                      \
      const float alpha = __builtin_amdgcn_exp2f(mold - mnew);                 \
      mi[t][r] = mnew;                                                         \
      const float p0 = __builtin_amdgcn_exp2f(S[0][r] - mnew);                 \
      const float p1 = __builtin_amdgcn_exp2f(S[1][r] - mnew);                 \
      const float p2 = __builtin_amdgcn_exp2f(S[2][r] - mnew);                 \
      const float p3 = __builtin_amdgcn_exp2f(S[3][r] - mnew);                 \
      liacc[t][r] *= alpha;                                                    \
      _Pragma("unroll")                                                        \
      for (int dt = 0; dt < 4; ++dt) O[t][dt][r] *= alpha;                     \
      const u64 pk = (u64)pack_trunc(p0, p1) |                                 \
                     ((u64)pack_trunc(p2, p3) << 32);                          \
      *(u64*)&(Pw)[(quad * 4 + r) * 72 + 4 * l15] = pk;                        \
    }                                                                          \
    s16x8 a0 = *(const s16x8*)&(Pw)[l15 * 72 + quad * 8];                      \
    s16x8 a1 = *(const s16x8*)&(Pw)[l15 * 72 + 32 + quad * 8];                 \
    liacc[t] = __builtin_amdgcn_mfma_f32_16x16x32_bf16(a0, ones, liacc[t], 0, 0, 0); \
    liacc[t] = __builtin_amdgcn_mfma_f32_16x16x32_bf16(a1, ones, liacc[t], 0, 0, 0); \
    _Pragma("unroll")                                                          \
    for (int dt = 0; dt < 4; ++dt) {                                           \
      s16x8 b0 = *(const s16x8*)&Vt[(dt * 16 + l15) * 72 + quad * 8];          \
      s16x8 b1 = *(const s16x8*)&Vt[(dt * 16 + l15) * 72 + 32 + quad * 8];     \
      O[t][dt] = __builtin_amdgcn_mfma_f32_16x16x32_bf16(a0, b0, O[t][dt], 0, 0, 0); \
      O[t][dt] = __builtin_amdgcn_mfma_f32_16x16x32_bf16(a1, b1, O[t][dt], 0, 0, 0); \
    }                                                                          \
  } while (0)

__global__ __launch_bounds__(256, 4)
void attn_kernel(const u16* __restrict__ Qg, const u16* __restrict__ Kg,
                 const u16* __restrict__ VTg, u16* __restrict__ out)
{
  const int pi = blockIdx.x;
  const int bh = blockIdx.y;
  const int b = bh >> 4, h = bh & 15;
  const int qt0 = 31 - pi;            // heavy tile
  const int qt1 = pi;                 // light tile

  __shared__ u16 Qs[128 * 72];        // rows 0-63: qt0, 64-127: qt1; P scratch
  __shared__ u16 Ks[64 * 72];
  __shared__ u16 Vt[64 * 72];

  const int tid = threadIdx.x;
  const int w = tid >> 6, lane = tid & 63, quad = lane >> 4, l15 = lane & 15;
  const size_t base = (size_t)bh * 131072;

  {
    const int col = (tid & 7) * 8;
    #pragma unroll
    for (int p = 0; p < 4; ++p) {
      const int row = (tid >> 3) + p * 32;
      const int gq = (row < 64) ? (qt0 * 64 + row) : (qt1 * 64 + (row - 64));
      *(s16x8*)&Qs[row * 72 + col] =
          *(const s16x8*)(Qg + base + (size_t)gq * 64 + col);
    }
  }
  __syncthreads();

  // per-wave 16-row slices: tile t rows [t*64 + w*16, +16)
  s16x8 aq[2][2];
  #pragma unroll
  for (int t = 0; t < 2; ++t)
    #pragma unroll
    for (int ks = 0; ks < 2; ++ks)
      aq[t][ks] = *(const s16x8*)&Qs[(t * 64 + w * 16 + l15) * 72 + ks * 32 + quad * 8];

  u16* Pw0 = &Qs[(w * 16) * 72];
  u16* Pw1 = &Qs[(64 + w * 16) * 72];

  s16x8 ones;
  #pragma unroll
  for (int e = 0; e < 8; ++e) ones[e] = (short)0x3F80;

  f32x4 O[2][4], liacc[2];
  float mi[2][4];
  #pragma unroll
  for (int t = 0; t < 2; ++t) {
    #pragma unroll
    for (int dt = 0; dt < 4; ++dt) O[t][dt] = (f32x4){0.f, 0.f, 0.f, 0.f};
    liacc[t] = (f32x4){0.f, 0.f, 0.f, 0.f};
    #pragma unroll
    for (int r = 0; r < 4; ++r) mi[t][r] = -1e30f;
  }

  for (int j = 0; j <= qt0; ++j) {
    #pragma unroll
    for (int p = 0; p < 2; ++p) {
      const int idx = tid + p * 256;
      const int key = idx >> 3, col = (idx & 7) * 8;
      const int slot = (key & 3) * 16 + (key >> 2);
      *(s16x8*)&Ks[slot * 72 + col] =
          *(const s16x8*)(Kg + base + (size_t)(j * 64 + key) * 64 + col);
    }
    #pragma unroll
    for (int p = 0; p < 2; ++p) {
      const int idx = tid + p * 256;
      const int d = idx >> 3, col = (idx & 7) * 8;
      *(s16x8*)&Vt[d * 72 + col] =
          *(const s16x8*)(VTg + base + (size_t)d * 2048 + j * 64 + col);
    }
    __syncthreads();

    ATTN_STEP(0, Pw0, qt0);
    if (j <= qt1) ATTN_STEP(1, Pw1, qt1);   // block-uniform scalar branch
    __syncthreads();
  }

  #pragma unroll
  for (int t = 0; t < 2; ++t) {
    const int qtt = t ? qt1 : qt0;
    #pragma unroll
    for (int r = 0; r < 4; ++r) {
      const float inv = __builtin_amdgcn_rcpf(liacc[t][r]);
      const int sq = qtt * 64 + w * 16 + quad * 4 + r;
      #pragma unroll
      for (int dt = 0; dt < 4; ++dt)
        out[(size_t)(b * 2048 + sq) * 1024 + h * 64 + dt * 16 + l15] =
            f2bf(O[t][dt][r] * inv);
    }
  }
}

extern "C" void kernel_launch(void* const* d_in, const int* in_sizes, int n_in,
                              void* d_out, int out_size, void* d_ws, size_t ws_size,
                              hipStream_t stream) {
  (void)in_sizes; (void)n_in; (void)out_size; (void)ws_size;
  const float* x  = (const float*)d_in[0];
  const float* Wq = (const float*)d_in[1];
  const float* Wk = (const float*)d_in[2];
  const float* Wv = (const float*)d_in[3];
  const float* Wo = (const float*)d_in[4];
  float* out = (float*)d_out;

  u16* W16 = (u16*)d_ws;
  u16* xb  = W16;
  u16* VT  = W16;                 // alias: x dead after QKV gemm
  u16* Qb  = W16 + 8388608;
  u16* Kb  = W16 + 16777216;
  u16* Vb  = W16 + 25165824;
  u16* AO  = Vb;                  // alias: V natural layout dead after vtrans
  u16* Wqb = W16 + 33554432;
  u16* Wkb = Wqb + 1048576;
  u16* Wvb = Wkb + 1048576;
  u16* Wob = Wvb + 1048576;

  dim3 blk(256);
  cvt_bf16<<<dim3(4096), blk, 0, stream>>>(x,  xb,  1048576);
  cvt_bf16<<<dim3(512),  blk, 0, stream>>>(Wq, Wqb, 131072);
  cvt_bf16<<<dim3(512),  blk, 0, stream>>>(Wk, Wkb, 131072);
  cvt_bf16<<<dim3(512),  blk, 0, stream>>>(Wv, Wvb, 131072);
  cvt_bf16<<<dim3(512),  blk, 0, stream>>>(Wo, Wob, 131072);

  gemm97<true ><<<dim3(64, 8, 3), blk, 0, stream>>>(
      xb, Wqb, Wkb, Wvb, Qb, Kb, Vb, nullptr);
  vtrans<<<dim3(32, 64), blk, 0, stream>>>(Vb, VT);
  attn_kernel<<<dim3(16, 64), blk, 0, stream>>>(Qb, Kb, VT, AO);
  gemm97<false><<<dim3(64, 8, 1), blk, 0, stream>>>(
      AO, Wob, Wob, Wob, nullptr, nullptr, nullptr, out);
}